// Round 6
// baseline (362.335 us; speedup 1.0000x reference)
//
#include <hip/hip_runtime.h>
#include <hip/hip_bf16.h>

typedef float f32x4 __attribute__((ext_vector_type(4)));
typedef short s16x8 __attribute__((ext_vector_type(8)));

#define B_ 4
#define S_ 2048
#define D_ 768

// keep-alive pin: forbids the compiler from sinking/rematerializing a load
#define PIN(x) asm volatile("" :: "v"(x))

typedef const __attribute__((address_space(1))) char* gas_t;
typedef __attribute__((address_space(3))) char* las_t;

__device__ __forceinline__ void gload_lds16(const void* g, void* l) {
  __builtin_amdgcn_global_load_lds((gas_t)g, (las_t)l, 16, 0, 0);
}

// ---------------- f32 -> bf16 conversion ----------------
__global__ void cvt_kernel(const float* __restrict__ x,
                           const float* __restrict__ wq,
                           const float* __restrict__ wk,
                           const float* __restrict__ wv,
                           __hip_bfloat16* __restrict__ xb,
                           __hip_bfloat16* __restrict__ wqb,
                           __hip_bfloat16* __restrict__ wkb,
                           __hip_bfloat16* __restrict__ wvb) {
  const int NX = B_ * S_ * D_ / 4;
  const int NW = D_ * D_ / 4;
  int stride = gridDim.x * blockDim.x;
  for (int j = blockIdx.x * blockDim.x + threadIdx.x; j < NX + 3 * NW; j += stride) {
    const float4* src; __hip_bfloat16* dst; int off;
    if (j < NX)             { src = (const float4*)x;  dst = xb;  off = j; }
    else if (j < NX + NW)   { src = (const float4*)wq; dst = wqb; off = j - NX; }
    else if (j < NX + 2*NW) { src = (const float4*)wk; dst = wkb; off = j - NX - NW; }
    else                    { src = (const float4*)wv; dst = wvb; off = j - NX - 2*NW; }
    float4 v = src[off];
    dst[4*off+0] = __float2bfloat16(v.x);
    dst[4*off+1] = __float2bfloat16(v.y);
    dst[4*off+2] = __float2bfloat16(v.z);
    dst[4*off+3] = __float2bfloat16(v.w);
  }
}

// ---------------- QKV projection GEMM ----------------
// z=0: Q = x @ Wq^T ; z=1: K = x @ Wk^T ; z=2: Vt = Wv @ x^T (V transposed [B][768][2048])
__launch_bounds__(256, 3)
__global__ void qkv_gemm(const __hip_bfloat16* __restrict__ xb,
                         const __hip_bfloat16* __restrict__ wqb,
                         const __hip_bfloat16* __restrict__ wkb,
                         const __hip_bfloat16* __restrict__ wvb,
                         __hip_bfloat16* __restrict__ Qb,
                         __hip_bfloat16* __restrict__ Kb,
                         __hip_bfloat16* __restrict__ Vt) {
  __shared__ __hip_bfloat16 At[128 * 32];
  __shared__ __hip_bfloat16 Bt[128 * 32];
  const int z = blockIdx.z;
  const __hip_bfloat16* Ag;
  const __hip_bfloat16* Bg;
  int m0, n0;
  if (z == 0)      { Ag = xb;  Bg = wqb; m0 = blockIdx.x * 128; n0 = blockIdx.y * 128; }
  else if (z == 1) { Ag = xb;  Bg = wkb; m0 = blockIdx.x * 128; n0 = blockIdx.y * 128; }
  else             { Ag = wvb; Bg = xb;  m0 = blockIdx.y * 128; n0 = blockIdx.x * 128; }

  const int tid = threadIdx.x, w = tid >> 6, l = tid & 63;
  const int wr = w >> 1, wc = w & 1;
  f32x4 acc[4][4] = {};

  for (int k0 = 0; k0 < 768; k0 += 32) {
    __syncthreads();
#pragma unroll
    for (int j = 0; j < 2; ++j) {
      int ra = w * 16 + j * 64 + (l >> 2);
      gload_lds16(Ag + (size_t)(m0 + ra) * 768 + k0 + (l & 3) * 8,
                  (char*)At + w * 1024 + j * 4096);
      gload_lds16(Bg + (size_t)(n0 + ra) * 768 + k0 + (l & 3) * 8,
                  (char*)Bt + w * 1024 + j * 4096);
    }
    __syncthreads();
    s16x8 a[4], b[4];
#pragma unroll
    for (int i = 0; i < 4; ++i) {
      a[i] = *(const s16x8*)&At[(wr * 64 + i * 16 + (l & 15)) * 32 + (l >> 4) * 8];
      b[i] = *(const s16x8*)&Bt[(wc * 64 + i * 16 + (l & 15)) * 32 + (l >> 4) * 8];
    }
#pragma unroll
    for (int i = 0; i < 4; ++i)
#pragma unroll
      for (int j = 0; j < 4; ++j)
        acc[i][j] = __builtin_amdgcn_mfma_f32_16x16x32_bf16(a[i], b[j], acc[i][j], 0, 0, 0);
  }

  if (z < 2) {
    __hip_bfloat16* outp = (z == 0) ? Qb : Kb;
#pragma unroll
    for (int i = 0; i < 4; ++i) {
      int m = m0 + wr * 64 + i * 16 + (l >> 4) * 4;
#pragma unroll
      for (int j = 0; j < 4; ++j) {
        int n = n0 + wc * 64 + j * 16 + (l & 15);
#pragma unroll
        for (int r = 0; r < 4; ++r)
          outp[(size_t)(m + r) * 768 + n] = __float2bfloat16(acc[i][j][r]);
      }
    }
  } else {
#pragma unroll
    for (int i = 0; i < 4; ++i) {
      int dd = m0 + wr * 64 + i * 16 + (l >> 4) * 4;
#pragma unroll
      for (int j = 0; j < 4; ++j) {
        int sg = n0 + wc * 64 + j * 16 + (l & 15);
        int bb = sg >> 11, sl = sg & 2047;
#pragma unroll
        for (int r = 0; r < 4; ++r)
          Vt[(size_t)bb * D_ * S_ + (size_t)(dd + r) * S_ + sl] = __float2bfloat16(acc[i][j][r]);
      }
    }
  }
}

// ---------------- causal flash attention ----------------
// QBLK=16, KVBLK=128, 8 waves. K/V fragments are wave-exclusive -> direct
// global loads into PINNED register arrays (24 loads in flight each; the
// asm keep-alive stops the compiler sinking them to the MFMAs). V issues
// before softmax so its latency hides under the two reduce barriers.
__launch_bounds__(512, 2)
__global__ void flash_attn(const __hip_bfloat16* __restrict__ Qb,
                           const __hip_bfloat16* __restrict__ Kb,
                           const __hip_bfloat16* __restrict__ Vt,
                           float* __restrict__ out) {
  __shared__ __hip_bfloat16 Qs[16][776];
  __shared__ __hip_bfloat16 Ps[16][136];
  __shared__ float redm[16][8];  // [qrow][wave] -> float4-readable
  __shared__ float reds[16][8];

  const int id = blockIdx.x;
  const int b = (id & 7) >> 1;                // batch from XCD bits: 2 XCDs/batch
  const int p = ((id >> 3) << 1) | (id & 1);  // pair index 0..63
  const int tid = threadIdx.x, w = tid >> 6, l = tid & 63;
  const int g = l >> 4, c = l & 15;
  const float SC = 0.03608439182435161f * 1.4426950408889634f;  // (1/sqrt(768)) * log2(e)

#pragma unroll 1
  for (int half = 0; half < 2; ++half) {
    const int qt = (half == 0) ? p : 127 - p;
    const int q0 = qt * 16;
    for (int i = tid; i < 16 * 96; i += 512) {
      int row = i / 96, ch = i % 96;
      *(uint4*)&Qs[row][ch * 8] =
          *(const uint4*)&Qb[((size_t)b * S_ + q0 + row) * D_ + ch * 8];
    }
    f32x4 acc[6] = {};
    float m2[4], lsum[4];
#pragma unroll
    for (int r = 0; r < 4; ++r) { m2[r] = -1e30f; lsum[r] = 0.f; }
    __syncthreads();

    const int nkv = (q0 + 143) >> 7;
    const __hip_bfloat16* krow = Kb + ((size_t)b * S_ + w * 16 + c) * D_ + g * 8;
    const __hip_bfloat16* vrow = Vt + (size_t)b * D_ * S_ + (size_t)(w * 96 + c) * S_ + g * 8;
#pragma unroll 1
    for (int t = 0; t < nkv; ++t) {
      const int kv0 = t * 128;
      // ---- K fragment prefetch: 24 pinned loads, all in flight ----
      const __hip_bfloat16* kb = krow + (size_t)kv0 * D_;
      s16x8 kf[24];
#pragma unroll
      for (int kk = 0; kk < 24; ++kk) {
        kf[kk] = *(const s16x8*)&kb[kk * 32];
        PIN(kf[kk]);
      }
      // ---- QK^T: wave w owns kv rows [kv0+w*16, kv0+w*16+16) ----
      f32x4 s0 = {}, s1 = {};
#pragma unroll
      for (int kk = 0; kk < 24; ++kk) {
        s16x8 a = *(const s16x8*)&Qs[c][kk * 32 + g * 8];
        if (kk & 1) s1 = __builtin_amdgcn_mfma_f32_16x16x32_bf16(a, kf[kk], s1, 0, 0, 0);
        else        s0 = __builtin_amdgcn_mfma_f32_16x16x32_bf16(a, kf[kk], s0, 0, 0, 0);
      }
      // ---- V fragment prefetch: 24 pinned loads; land during softmax ----
      s16x8 vf[24];
#pragma unroll
      for (int ks = 0; ks < 4; ++ks)
#pragma unroll
        for (int i2 = 0; i2 < 6; ++i2) {
          vf[ks * 6 + i2] = *(const s16x8*)&vrow[(size_t)(i2 * 16) * S_ + kv0 + ks * 32];
          PIN(vf[ks * 6 + i2]);
        }
      // ---- online softmax (lane holds q-rows g*4+r, kpos w*16+c) ----
      float z[4], mx[4];
#pragma unroll
      for (int r = 0; r < 4; ++r) {
        float zz = (s0[r] + s1[r]) * SC;
        int kpos = kv0 + w * 16 + c;
        int qrow = q0 + g * 4 + r;
        zz = (kpos > qrow) ? -1e30f : zz;
        z[r] = zz; mx[r] = zz;
      }
#pragma unroll
      for (int dd = 1; dd < 16; dd <<= 1)
#pragma unroll
        for (int r = 0; r < 4; ++r)
          mx[r] = fmaxf(mx[r], __shfl_xor(mx[r], dd, 64));
      if (c == 0) {
#pragma unroll
        for (int r = 0; r < 4; ++r) redm[g * 4 + r][w] = mx[r];
      }
      __syncthreads();
      float mnew[4], alpha[4];
#pragma unroll
      for (int r = 0; r < 4; ++r) {
        const float4* q4 = (const float4*)&redm[g * 4 + r][0];
        float4 a0 = q4[0], a1 = q4[1];
        float mm = fmaxf(fmaxf(fmaxf(a0.x, a0.y), fmaxf(a0.z, a0.w)),
                         fmaxf(fmaxf(a1.x, a1.y), fmaxf(a1.z, a1.w)));
        mnew[r] = fmaxf(m2[r], mm);
        alpha[r] = exp2f(m2[r] - mnew[r]);
        m2[r] = mnew[r];
      }
      float pr[4], ps[4];
#pragma unroll
      for (int r = 0; r < 4; ++r) { pr[r] = exp2f(z[r] - mnew[r]); ps[r] = pr[r]; }
#pragma unroll
      for (int dd = 1; dd < 16; dd <<= 1)
#pragma unroll
        for (int r = 0; r < 4; ++r) ps[r] += __shfl_xor(ps[r], dd, 64);
      if (c == 0) {
#pragma unroll
        for (int r = 0; r < 4; ++r) reds[g * 4 + r][w] = ps[r];
      }
#pragma unroll
      for (int r = 0; r < 4; ++r) Ps[g * 4 + r][w * 16 + c] = __float2bfloat16(pr[r]);
#pragma unroll
      for (int i = 0; i < 6; ++i)
#pragma unroll
        for (int r = 0; r < 4; ++r) acc[i][r] *= alpha[r];
      __syncthreads();  // Ps + reds visible
#pragma unroll
      for (int r = 0; r < 4; ++r) {
        const float4* q4 = (const float4*)&reds[g * 4 + r][0];
        float4 a0 = q4[0], a1 = q4[1];
        float ss = (a0.x + a0.y) + (a0.z + a0.w) + (a1.x + a1.y) + (a1.z + a1.w);
        lsum[r] = lsum[r] * alpha[r] + ss;
      }
      // ---- PV: wave w owns d range [w*96, w*96+96), V already in regs ----
#pragma unroll
      for (int ks = 0; ks < 4; ++ks) {
        s16x8 a = *(const s16x8*)&Ps[c][ks * 32 + g * 8];
#pragma unroll
        for (int i2 = 0; i2 < 6; ++i2)
          acc[i2] = __builtin_amdgcn_mfma_f32_16x16x32_bf16(a, vf[ks * 6 + i2], acc[i2], 0, 0, 0);
      }
    }  // kv loop
    // ---- epilogue ----
#pragma unroll
    for (int i = 0; i < 6; ++i)
#pragma unroll
      for (int r = 0; r < 4; ++r) {
        int qrow = q0 + g * 4 + r;
        out[(size_t)b * S_ * D_ + (size_t)qrow * D_ + w * 96 + i * 16 + c] =
            acc[i][r] / lsum[r];
      }
    __syncthreads();  // before Qs reload for second half
  }
}

extern "C" void kernel_launch(void* const* d_in, const int* in_sizes, int n_in,
                              void* d_out, int out_size, void* d_ws, size_t ws_size,
                              hipStream_t stream) {
  const float* x  = (const float*)d_in[0];
  const float* wq = (const float*)d_in[1];
  const float* wk = (const float*)d_in[2];
  const float* wv = (const float*)d_in[3];
  char* ws = (char*)d_ws;
  __hip_bfloat16* xb  = (__hip_bfloat16*)(ws + 0);
  __hip_bfloat16* wqb = (__hip_bfloat16*)(ws + 12582912);
  __hip_bfloat16* wkb = (__hip_bfloat16*)(ws + 12582912 + 1179648);
  __hip_bfloat16* wvb = (__hip_bfloat16*)(ws + 12582912 + 2 * 1179648);
  __hip_bfloat16* Qb  = (__hip_bfloat16*)(ws + 16121856);
  __hip_bfloat16* Kb  = (__hip_bfloat16*)(ws + 28704768);
  __hip_bfloat16* Vt  = (__hip_bfloat16*)(ws + 41287680);

  cvt_kernel<<<2048, 256, 0, stream>>>(x, wq, wk, wv, xb, wqb, wkb, wvb);
  qkv_gemm<<<dim3(64, 6, 3), 256, 0, stream>>>(xb, wqb, wkb, wvb, Qb, Kb, Vt);
  flash_attn<<<dim3(256), 512, 0, stream>>>(Qb, Kb, Vt, (float*)d_out);
}

// Round 7
// 215.056 us; speedup vs baseline: 1.6848x; 1.6848x over previous
//
#include <hip/hip_runtime.h>
#include <hip/hip_bf16.h>

typedef float f32x4 __attribute__((ext_vector_type(4)));
typedef short s16x8 __attribute__((ext_vector_type(8)));

#define B_ 4
#define S_ 2048
#define D_ 768

typedef const __attribute__((address_space(1))) char* gas_t;
typedef __attribute__((address_space(3))) char* las_t;

__device__ __forceinline__ void gload_lds16(const void* g, void* l) {
  __builtin_amdgcn_global_load_lds((gas_t)g, (las_t)l, 16, 0, 0);
}

// ---------------- f32 -> bf16 conversion ----------------
__global__ void cvt_kernel(const float* __restrict__ x,
                           const float* __restrict__ wq,
                           const float* __restrict__ wk,
                           const float* __restrict__ wv,
                           __hip_bfloat16* __restrict__ xb,
                           __hip_bfloat16* __restrict__ wqb,
                           __hip_bfloat16* __restrict__ wkb,
                           __hip_bfloat16* __restrict__ wvb) {
  const int NX = B_ * S_ * D_ / 4;
  const int NW = D_ * D_ / 4;
  int stride = gridDim.x * blockDim.x;
  for (int j = blockIdx.x * blockDim.x + threadIdx.x; j < NX + 3 * NW; j += stride) {
    const float4* src; __hip_bfloat16* dst; int off;
    if (j < NX)             { src = (const float4*)x;  dst = xb;  off = j; }
    else if (j < NX + NW)   { src = (const float4*)wq; dst = wqb; off = j - NX; }
    else if (j < NX + 2*NW) { src = (const float4*)wk; dst = wkb; off = j - NX - NW; }
    else                    { src = (const float4*)wv; dst = wvb; off = j - NX - 2*NW; }
    float4 v = src[off];
    dst[4*off+0] = __float2bfloat16(v.x);
    dst[4*off+1] = __float2bfloat16(v.y);
    dst[4*off+2] = __float2bfloat16(v.z);
    dst[4*off+3] = __float2bfloat16(v.w);
  }
}

// ---------------- QKV projection GEMM ----------------
// z=0: Q = x @ Wq^T ; z=1: K = x @ Wk^T ; z=2: Vt = Wv @ x^T (V transposed [B][768][2048])
__launch_bounds__(256, 3)
__global__ void qkv_gemm(const __hip_bfloat16* __restrict__ xb,
                         const __hip_bfloat16* __restrict__ wqb,
                         const __hip_bfloat16* __restrict__ wkb,
                         const __hip_bfloat16* __restrict__ wvb,
                         __hip_bfloat16* __restrict__ Qb,
                         __hip_bfloat16* __restrict__ Kb,
                         __hip_bfloat16* __restrict__ Vt) {
  __shared__ __hip_bfloat16 At[128 * 32];
  __shared__ __hip_bfloat16 Bt[128 * 32];
  const int z = blockIdx.z;
  const __hip_bfloat16* Ag;
  const __hip_bfloat16* Bg;
  int m0, n0;
  if (z == 0)      { Ag = xb;  Bg = wqb; m0 = blockIdx.x * 128; n0 = blockIdx.y * 128; }
  else if (z == 1) { Ag = xb;  Bg = wkb; m0 = blockIdx.x * 128; n0 = blockIdx.y * 128; }
  else             { Ag = wvb; Bg = xb;  m0 = blockIdx.y * 128; n0 = blockIdx.x * 128; }

  const int tid = threadIdx.x, w = tid >> 6, l = tid & 63;
  const int wr = w >> 1, wc = w & 1;
  f32x4 acc[4][4] = {};

  for (int k0 = 0; k0 < 768; k0 += 32) {
    __syncthreads();
#pragma unroll
    for (int j = 0; j < 2; ++j) {
      int ra = w * 16 + j * 64 + (l >> 2);
      gload_lds16(Ag + (size_t)(m0 + ra) * 768 + k0 + (l & 3) * 8,
                  (char*)At + w * 1024 + j * 4096);
      gload_lds16(Bg + (size_t)(n0 + ra) * 768 + k0 + (l & 3) * 8,
                  (char*)Bt + w * 1024 + j * 4096);
    }
    __syncthreads();
    s16x8 a[4], b[4];
#pragma unroll
    for (int i = 0; i < 4; ++i) {
      a[i] = *(const s16x8*)&At[(wr * 64 + i * 16 + (l & 15)) * 32 + (l >> 4) * 8];
      b[i] = *(const s16x8*)&Bt[(wc * 64 + i * 16 + (l & 15)) * 32 + (l >> 4) * 8];
    }
#pragma unroll
    for (int i = 0; i < 4; ++i)
#pragma unroll
      for (int j = 0; j < 4; ++j)
        acc[i][j] = __builtin_amdgcn_mfma_f32_16x16x32_bf16(a[i], b[j], acc[i][j], 0, 0, 0);
  }

  if (z < 2) {
    __hip_bfloat16* outp = (z == 0) ? Qb : Kb;
#pragma unroll
    for (int i = 0; i < 4; ++i) {
      int m = m0 + wr * 64 + i * 16 + (l >> 4) * 4;
#pragma unroll
      for (int j = 0; j < 4; ++j) {
        int n = n0 + wc * 64 + j * 16 + (l & 15);
#pragma unroll
        for (int r = 0; r < 4; ++r)
          outp[(size_t)(m + r) * 768 + n] = __float2bfloat16(acc[i][j][r]);
      }
    }
  } else {
#pragma unroll
    for (int i = 0; i < 4; ++i) {
      int dd = m0 + wr * 64 + i * 16 + (l >> 4) * 4;
#pragma unroll
      for (int j = 0; j < 4; ++j) {
        int sg = n0 + wc * 64 + j * 16 + (l & 15);
        int bb = sg >> 11, sl = sg & 2047;
#pragma unroll
        for (int r = 0; r < 4; ++r)
          Vt[(size_t)bb * D_ * S_ + (size_t)(dd + r) * S_ + sl] = __float2bfloat16(acc[i][j][r]);
      }
    }
  }
}

// ---------------- S = scale*log2e * Q K^T, causal-masked, bf16 ----------------
// Only lower-triangle tile-blocks (kt <= qt) computed; others never read.
__launch_bounds__(256, 3)
__global__ void qk_gemm(const __hip_bfloat16* __restrict__ Qb,
                        const __hip_bfloat16* __restrict__ Kb,
                        __hip_bfloat16* __restrict__ Sb) {
  __shared__ __hip_bfloat16 At[128 * 32];
  __shared__ __hip_bfloat16 Bt[128 * 32];
  const int qt = blockIdx.x, kt = blockIdx.y, b = blockIdx.z;
  if (kt > qt) return;
  const int m0 = qt * 128, n0 = kt * 128;
  const __hip_bfloat16* Ag = Qb + (size_t)b * S_ * D_;
  const __hip_bfloat16* Bg = Kb + (size_t)b * S_ * D_;
  const int tid = threadIdx.x, w = tid >> 6, l = tid & 63;
  const int wr = w >> 1, wc = w & 1;
  const float SC = 0.03608439182435161f * 1.4426950408889634f;  // (1/sqrt(768))*log2(e)
  f32x4 acc[4][4] = {};

  for (int k0 = 0; k0 < D_; k0 += 32) {
    __syncthreads();
#pragma unroll
    for (int j = 0; j < 2; ++j) {
      int ra = w * 16 + j * 64 + (l >> 2);
      gload_lds16(Ag + (size_t)(m0 + ra) * D_ + k0 + (l & 3) * 8,
                  (char*)At + w * 1024 + j * 4096);
      gload_lds16(Bg + (size_t)(n0 + ra) * D_ + k0 + (l & 3) * 8,
                  (char*)Bt + w * 1024 + j * 4096);
    }
    __syncthreads();
    s16x8 a[4], bfr[4];
#pragma unroll
    for (int i = 0; i < 4; ++i) {
      a[i]   = *(const s16x8*)&At[(wr * 64 + i * 16 + (l & 15)) * 32 + (l >> 4) * 8];
      bfr[i] = *(const s16x8*)&Bt[(wc * 64 + i * 16 + (l & 15)) * 32 + (l >> 4) * 8];
    }
#pragma unroll
    for (int i = 0; i < 4; ++i)
#pragma unroll
      for (int j = 0; j < 4; ++j)
        acc[i][j] = __builtin_amdgcn_mfma_f32_16x16x32_bf16(a[i], bfr[j], acc[i][j], 0, 0, 0);
  }

#pragma unroll
  for (int i = 0; i < 4; ++i) {
    int m = m0 + wr * 64 + i * 16 + (l >> 4) * 4;
#pragma unroll
    for (int j = 0; j < 4; ++j) {
      int n = n0 + wc * 64 + j * 16 + (l & 15);
#pragma unroll
      for (int r = 0; r < 4; ++r) {
        float zz = (n > m + r) ? -1e30f : acc[i][j][r] * SC;
        Sb[(size_t)(b * S_ + m + r) * S_ + n] = __float2bfloat16(zz);
      }
    }
  }
}

// ---------------- row softmax: P = exp2(S - m)/sum, bf16 ----------------
// One wave per q-row; row fully register-resident (<= 8 f32x4 per lane).
__launch_bounds__(256, 4)
__global__ void softmax_kernel(const __hip_bfloat16* __restrict__ Sb,
                               __hip_bfloat16* __restrict__ Pb) {
  const int tid = threadIdx.x, w = tid >> 6, l = tid & 63;
  const int r = blockIdx.x * 4 + w;
  const int q = r & (S_ - 1);
  const int L = ((q >> 7) + 1) << 7;  // row valid length, multiple of 128
  const ushort* srow = (const ushort*)(Sb + (size_t)r * S_);
  ushort* prow = (ushort*)(Pb + (size_t)r * S_);
  f32x4 ch[8];
#pragma unroll
  for (int it = 0; it < 8; ++it) {
    int idx = it * 256 + l * 4;
    if (idx < L) {
      ushort4 u = *(const ushort4*)&srow[idx];
      ch[it].x = __uint_as_float((unsigned)u.x << 16);
      ch[it].y = __uint_as_float((unsigned)u.y << 16);
      ch[it].z = __uint_as_float((unsigned)u.z << 16);
      ch[it].w = __uint_as_float((unsigned)u.w << 16);
    } else {
      ch[it].x = -1e30f; ch[it].y = -1e30f; ch[it].z = -1e30f; ch[it].w = -1e30f;
    }
  }
  float mx = -1e30f;
#pragma unroll
  for (int it = 0; it < 8; ++it)
    mx = fmaxf(mx, fmaxf(fmaxf(ch[it].x, ch[it].y), fmaxf(ch[it].z, ch[it].w)));
#pragma unroll
  for (int d = 1; d < 64; d <<= 1) mx = fmaxf(mx, __shfl_xor(mx, d, 64));
  float sum = 0.f;
#pragma unroll
  for (int it = 0; it < 8; ++it) {
    ch[it].x = exp2f(ch[it].x - mx);  // masked entries -> exp2(~-1e30) = 0
    ch[it].y = exp2f(ch[it].y - mx);
    ch[it].z = exp2f(ch[it].z - mx);
    ch[it].w = exp2f(ch[it].w - mx);
    sum += (ch[it].x + ch[it].y) + (ch[it].z + ch[it].w);
  }
#pragma unroll
  for (int d = 1; d < 64; d <<= 1) sum += __shfl_xor(sum, d, 64);
  const float rinv = 1.0f / sum;
#pragma unroll
  for (int it = 0; it < 8; ++it) {
    int idx = it * 256 + l * 4;
    if (idx < L) {
      __hip_bfloat16 h0 = __float2bfloat16(ch[it].x * rinv);
      __hip_bfloat16 h1 = __float2bfloat16(ch[it].y * rinv);
      __hip_bfloat16 h2 = __float2bfloat16(ch[it].z * rinv);
      __hip_bfloat16 h3 = __float2bfloat16(ch[it].w * rinv);
      ushort4 u;
      u.x = *(ushort*)&h0; u.y = *(ushort*)&h1; u.z = *(ushort*)&h2; u.w = *(ushort*)&h3;
      *(ushort4*)&prow[idx] = u;
    }
  }
}

// ---------------- O = P V  (A = P row-major k-contig, B = Vt row-major k-contig) ----
// K-loop bounded by causal length (qt+1)*128; long-K tiles launched first.
__launch_bounds__(256, 3)
__global__ void pv_gemm(const __hip_bfloat16* __restrict__ Pb,
                        const __hip_bfloat16* __restrict__ Vt,
                        float* __restrict__ out) {
  __shared__ __hip_bfloat16 At[128 * 32];
  __shared__ __hip_bfloat16 Bt[128 * 32];
  const int qt = 15 - (int)blockIdx.x, dt = blockIdx.y, b = blockIdx.z;
  const int m0 = qt * 128, n0 = dt * 128;
  const __hip_bfloat16* Ag = Pb + (size_t)b * S_ * S_;
  const __hip_bfloat16* Bg = Vt + (size_t)b * D_ * S_;
  const int tid = threadIdx.x, w = tid >> 6, l = tid & 63;
  const int wr = w >> 1, wc = w & 1;
  const int kmax = (qt + 1) * 128;
  f32x4 acc[4][4] = {};

  for (int k0 = 0; k0 < kmax; k0 += 32) {
    __syncthreads();
#pragma unroll
    for (int j = 0; j < 2; ++j) {
      int ra = w * 16 + j * 64 + (l >> 2);
      gload_lds16(Ag + (size_t)(m0 + ra) * S_ + k0 + (l & 3) * 8,
                  (char*)At + w * 1024 + j * 4096);
      gload_lds16(Bg + (size_t)(n0 + ra) * S_ + k0 + (l & 3) * 8,
                  (char*)Bt + w * 1024 + j * 4096);
    }
    __syncthreads();
    s16x8 a[4], bfr[4];
#pragma unroll
    for (int i = 0; i < 4; ++i) {
      a[i]   = *(const s16x8*)&At[(wr * 64 + i * 16 + (l & 15)) * 32 + (l >> 4) * 8];
      bfr[i] = *(const s16x8*)&Bt[(wc * 64 + i * 16 + (l & 15)) * 32 + (l >> 4) * 8];
    }
#pragma unroll
    for (int i = 0; i < 4; ++i)
#pragma unroll
      for (int j = 0; j < 4; ++j)
        acc[i][j] = __builtin_amdgcn_mfma_f32_16x16x32_bf16(a[i], bfr[j], acc[i][j], 0, 0, 0);
  }

#pragma unroll
  for (int i = 0; i < 4; ++i) {
    int m = m0 + wr * 64 + i * 16 + (l >> 4) * 4;
#pragma unroll
    for (int j = 0; j < 4; ++j) {
      int n = n0 + wc * 64 + j * 16 + (l & 15);
#pragma unroll
      for (int r = 0; r < 4; ++r)
        out[(size_t)(b * S_ + m + r) * D_ + n] = acc[i][j][r];
    }
  }
}

extern "C" void kernel_launch(void* const* d_in, const int* in_sizes, int n_in,
                              void* d_out, int out_size, void* d_ws, size_t ws_size,
                              hipStream_t stream) {
  const float* x  = (const float*)d_in[0];
  const float* wq = (const float*)d_in[1];
  const float* wk = (const float*)d_in[2];
  const float* wv = (const float*)d_in[3];
  char* ws = (char*)d_ws;
  // layout: xb 0..12.58M | w* ..16.12M | Qb ..28.70M | Kb ..41.29M | Vt ..53.87M
  //         Sb 53.87M..87.43M (bf16 scores)
  //         Pb 0..33.55M (overwrites xb/w*/Qb/Kb — all dead after qk_gemm)
  __hip_bfloat16* xb  = (__hip_bfloat16*)(ws + 0);
  __hip_bfloat16* wqb = (__hip_bfloat16*)(ws + 12582912);
  __hip_bfloat16* wkb = (__hip_bfloat16*)(ws + 12582912 + 1179648);
  __hip_bfloat16* wvb = (__hip_bfloat16*)(ws + 12582912 + 2 * 1179648);
  __hip_bfloat16* Qb  = (__hip_bfloat16*)(ws + 16121856);
  __hip_bfloat16* Kb  = (__hip_bfloat16*)(ws + 28704768);
  __hip_bfloat16* Vt  = (__hip_bfloat16*)(ws + 41287680);
  __hip_bfloat16* Sb  = (__hip_bfloat16*)(ws + 53870592);
  __hip_bfloat16* Pb  = (__hip_bfloat16*)(ws + 0);

  cvt_kernel<<<2048, 256, 0, stream>>>(x, wq, wk, wv, xb, wqb, wkb, wvb);
  qkv_gemm<<<dim3(64, 6, 3), 256, 0, stream>>>(xb, wqb, wkb, wvb, Qb, Kb, Vt);
  qk_gemm<<<dim3(16, 16, 4), 256, 0, stream>>>(Qb, Kb, Sb);
  softmax_kernel<<<2048, 256, 0, stream>>>(Sb, Pb);
  pv_gemm<<<dim3(16, 6, 4), 256, 0, stream>>>(Pb, Vt, (float*)d_out);
}